// Round 12
// baseline (186.999 us; speedup 1.0000x reference)
//
#include <hip/hip_runtime.h>
#include <hip/hip_bf16.h>

#define BN 8192      // batch rows
#define MM 8199      // real rows (BN + 7 centers)
#define MP 8208      // padded to multiple of 16
#define HH 128       // feature dim
#define EE 256       // center embedding dim
#define TSUP 64      // 128-row super-tiles over the 8192 batch rows
#define NTRI 2080    // TSUP*(TSUP+1)/2 triangular blocks
#define NUM_HIST 7

typedef __attribute__((ext_vector_type(8))) short short8;   // 8 bf16 = 4 VGPRs
typedef __attribute__((ext_vector_type(4))) float floatx4;

// ============================================================================
// TRANSPOSED LAYOUT rnt (r7, measured -32%): MFMA-fragment order. Tile t
// (16 rows), k-block kblk (8 bf16), col: bf16 addr = t*2048 + kblk*128 + col*8.
// Fragment kk load = base + t*2048 + kk*512 + lane*8 -> contiguous 1KB/wave.
//
// r9 ~36us (LDS-shared B), r10 ~31us (T14 split + pair barriers + diag hoist),
// r11 null (halved LDS traffic -> LDS port not binding). Conclusion: cost is
// per-ELEMENT epilogue (5 VALU + 1 exp per element on 67.2M elements).
// r12: SYMMETRY HALVING. cos is symmetric and the label-match is symmetric, so
// compute only upper-triangle 128x128 super-tile pairs (I<=J) and scatter each
// tile's row-sums to tot/pos[i] AND col-sums to tot/pos[j]. 67.2M -> 34.2M
// elements: half the MFMA, half the exp, half the epilogue.
//  - off-diag blocks: +per-j-tile col reduction (2 shfl_xor) -> LDS redc[256]
//    -> 256 global atomics at end.  - diag blocks: row sums only; also own the
//    centers strip (tile 512). Every (i,j) covered exactly once.
// History: r1 (256,5)=spill disaster; r3 __threadfence=L2 disaster; r4/r8
// occupancy-null; r5 VALU-count-null; r6 pipeline-null (pre-coalescing).
// ============================================================================

// ---- prep kernel: fuses {zero tot/pos, centers GEMV, row-normalize+transpose}
__global__ __launch_bounds__(256)
void prep_kernel(const float* __restrict__ reps,
                 const int* __restrict__ labels,
                 const float* __restrict__ centers,
                 const float* __restrict__ fc_w,
                 const float* __restrict__ fc_b,
                 __hip_bfloat16* __restrict__ rnt,
                 int* __restrict__ labp,
                 float* __restrict__ tot) {  // pos = tot + BN (contiguous)
  const int wid = threadIdx.x >> 6, lane = threadIdx.x & 63;
  const int b = blockIdx.x;
  if (b < 2048) {
    if (threadIdx.x < 8) tot[b * 8 + threadIdx.x] = 0.f;   // zeroes tot+pos (16384 floats)
    const int r = b * 4 + wid;
    float2 v = ((const float2*)(reps + (size_t)r * HH))[lane];   // k = 2*lane, 2*lane+1
    float ss = v.x * v.x + v.y * v.y;
#pragma unroll
    for (int m = 1; m < 64; m <<= 1) ss += __shfl_xor(ss, m);
    float inv = 1.0f / fmaxf(sqrtf(ss), 1e-8f);
    __hip_bfloat162 h2;
    h2.x = __float2bfloat16(v.x * inv);
    h2.y = __float2bfloat16(v.y * inv);
    // transposed store: bf16 addr = (r>>4)*2048 + (lane>>2)*128 + (r&15)*8 + 2*(lane&3)
    size_t o = (size_t)(r >> 4) * 1024 + (lane >> 2) * 64 + (r & 15) * 4 + (lane & 3);
    ((__hip_bfloat162*)rnt)[o] = h2;
    if (lane == 0) labp[r] = labels[r];
  } else {
    // ---- block 2048: centers @ fc_w^T + fc_b  -> LDS, then padded rows
    __shared__ float currs[7 * HH];
    for (int o = threadIdx.x; o < 7 * HH; o += 256) {
      int c = o >> 7, h = o & 127;
      const float4* ce = (const float4*)(centers + c * EE);
      const float4* w  = (const float4*)(fc_w + h * EE);
      float s = 0.f;
#pragma unroll 4
      for (int j = 0; j < EE / 4; ++j) {
        float4 a = ce[j], bb = w[j];
        s += a.x * bb.x + a.y * bb.y + a.z * bb.z + a.w * bb.w;
      }
      currs[o] = s + fc_b[h];
    }
    __syncthreads();
    // rows 8192..8207 (j-tile 512): wave wid handles 4 rows; zeros for c>=7
    for (int k = 0; k < 4; ++k) {
      int c = wid * 4 + k;            // 0..15
      int r = BN + c;
      float2 v = make_float2(0.f, 0.f);
      if (c < 7) v = ((const float2*)(currs + c * HH))[lane];
      float ss = v.x * v.x + v.y * v.y;
#pragma unroll
      for (int m = 1; m < 64; m <<= 1) ss += __shfl_xor(ss, m);
      float inv = 1.0f / fmaxf(sqrtf(ss), 1e-8f);
      __hip_bfloat162 h2;
      h2.x = __float2bfloat16(v.x * inv);
      h2.y = __float2bfloat16(v.y * inv);
      size_t o = (size_t)(r >> 4) * 1024 + (lane >> 2) * 64 + (r & 15) * 4 + (lane & 3);
      ((__hip_bfloat162*)rnt)[o] = h2;
      if (lane == 0) labp[r] = (r < MM) ? r - BN : -1;
    }
  }
}

// ---- main kernel (triangular): block (I,J), I<=J, computes the 128x128 tile
// of e_ij = exp2((cos-1)*K2') for i in super-tile I, j in super-tile J.
// Row-sums -> tot/pos[i]; for I<J also col-sums -> tot/pos[j] (symmetry).
__global__ __launch_bounds__(256, 2)
void main_kernel(const __hip_bfloat16* __restrict__ rnt,
                 const int* __restrict__ labp,
                 float* __restrict__ tot,
                 float* __restrict__ pos) {
  __shared__ short lbuf[2][4096];    // double-buffered 8KB j-tile PAIR
  __shared__ float redc[256];        // [0..127] col tot, [128..255] col pos
  const int lane = threadIdx.x & 63;
  const int w    = threadIdx.x >> 6;
  const int q = lane >> 4, col = lane & 15;
  const short* rns = (const short*)rnt;

  // ---- decode triangular block index -> (I, J), J >= I
  // base(I) = I*TSUP - I*(I-1)/2 ; I via closed form + exact fixup
  const int idx = blockIdx.x;
  int I = (int)(64.5f - sqrtf(4160.25f - 2.0f * (float)idx));
  I = (I < 0) ? 0 : ((I > TSUP - 1) ? TSUP - 1 : I);
  while (I * TSUP - (I * (I - 1)) / 2 > idx) --I;
  while ((I + 1) * TSUP - ((I + 1) * I) / 2 <= idx) ++I;
  const int J = I + (idx - (I * TSUP - (I * (I - 1)) / 2));
  const bool offdiag = (I != J);

  redc[threadIdx.x] = 0.f;

  // A fragments: wave w owns i-tiles ti[it] = I*8 + w*2 + it (128 rows/block)
  short8 afrag[2][4];
  int tix[2];
#pragma unroll
  for (int it = 0; it < 2; ++it) {
    tix[it] = I * 8 + w * 2 + it;
    const short* base = rns + (size_t)tix[it] * 2048 + lane * 8;
    afrag[it][0] = *(const short8*)(base);
    afrag[it][1] = *(const short8*)(base + 512);
    afrag[it][2] = *(const short8*)(base + 1024);
    afrag[it][3] = *(const short8*)(base + 1536);
  }
  int labi[2][4];
#pragma unroll
  for (int it = 0; it < 2; ++it)
#pragma unroll
    for (int r = 0; r < 4; ++r)
      labi[it][r] = labp[tix[it] * 16 + q * 4 + r];

  float stot[2][4] = {};
  float spos[2][4] = {};
  const float K2 = 10.30496147f;  // 0.5/0.07 * log2(e)

  // accumulate one j-tile; row sums into stot/spos, col partials into *ct/*cp
  auto accum = [&](short8 b0, short8 b1, short8 b2, short8 b3, int t, int labj,
                   float* ct, float* cp) {
#pragma unroll
    for (int it = 0; it < 2; ++it) {
      floatx4 acc = {0.f, 0.f, 0.f, 0.f};
      acc = __builtin_amdgcn_mfma_f32_16x16x32_bf16(afrag[it][0], b0, acc, 0, 0, 0);
      acc = __builtin_amdgcn_mfma_f32_16x16x32_bf16(afrag[it][1], b1, acc, 0, 0, 0);
      acc = __builtin_amdgcn_mfma_f32_16x16x32_bf16(afrag[it][2], b2, acc, 0, 0, 0);
      acc = __builtin_amdgcn_mfma_f32_16x16x32_bf16(afrag[it][3], b3, acc, 0, 0, 0);
      float ev[4];
#pragma unroll
      for (int r = 0; r < 4; ++r) {
        // C/D layout: row = q*4+r, col = lane&15 -> i = tix*16+q*4+r, j = t*16+col
        float e = __builtin_amdgcn_exp2f(fmaf(acc[r], K2, -K2));  // raw v_exp_f32
        ev[r] = e;
        float m = (labj == labi[it][r]) ? e : 0.f;
        stot[it][r] += e;
        spos[it][r] += m;
        if (ct) { *ct += e; *cp += m; }
      }
      if (t == tix[it]) {          // wave-uniform diagonal fix-up (I==J only)
#pragma unroll
        for (int r = 0; r < 4; ++r)
          if (col == q * 4 + r) { stot[it][r] -= ev[r]; spos[it][r] -= ev[r]; }
      }
    }
  };

  const int t0 = J * 8;   // 8 j-tiles per block

  // prologue: stage pair 0 (each thread 2x16B, coalesced); also covers redc init
  {
    const short* g = rns + (size_t)t0 * 2048 + threadIdx.x * 8;
    *(short8*)&lbuf[0][threadIdx.x * 8] = *(const short8*)g;
    *(short8*)&lbuf[0][2048 + threadIdx.x * 8] = *(const short8*)(g + 2048);
  }
  __syncthreads();

  for (int p = 0; p < 4; ++p) {
    const int cur = p & 1;
    const int t = t0 + p * 2;
    // T14 split: issue next pair's loads into regs NOW, ds_write after compute
    short8 nv0, nv1;
    const bool more = (p < 3);
    if (more) {
      const short* g = rns + (size_t)(t + 2) * 2048 + threadIdx.x * 8;
      nv0 = *(const short8*)g;
      nv1 = *(const short8*)(g + 2048);
    }
    const int labj0 = labp[t * 16 + col];
    const int labj1 = labp[t * 16 + 16 + col];

    const short* lb = &lbuf[cur][0];
#pragma unroll
    for (int u = 0; u < 2; ++u) {           // two tiles in the staged pair
      const short* s = lb + u * 2048;
      short8 b0 = *(const short8*)(s + lane * 8);
      short8 b1 = *(const short8*)(s + 512 + lane * 8);
      short8 b2 = *(const short8*)(s + 1024 + lane * 8);
      short8 b3 = *(const short8*)(s + 1536 + lane * 8);
      float ct = 0.f, cp = 0.f;
      accum(b0, b1, b2, b3, t + u, u ? labj1 : labj0,
            offdiag ? &ct : nullptr, offdiag ? &cp : nullptr);
      if (offdiag) {
        // col sums: reduce across the 4 q-groups (lanes col, col+16, +32, +48)
        ct += __shfl_xor(ct, 16); ct += __shfl_xor(ct, 32);
        cp += __shfl_xor(cp, 16); cp += __shfl_xor(cp, 32);
        if (q == 0) {
          int cj = (p * 2 + u) * 16 + col;        // 0..127 within J super-tile
          atomicAdd(&redc[cj], ct);
          atomicAdd(&redc[128 + cj], cp);
        }
      }
    }

    if (more) {   // vmcnt wait lands HERE, after the pair's compute
      *(short8*)&lbuf[cur ^ 1][threadIdx.x * 8] = nv0;
      *(short8*)&lbuf[cur ^ 1][2048 + threadIdx.x * 8] = nv1;
    }
    __syncthreads();
  }

  // diag blocks own the centers strip (tile 512, rows 8192..8207, row-side only)
  if (!offdiag) {
    const short* g = rns + (size_t)512 * 2048 + lane * 8;
    short8 b0 = *(const short8*)(g);
    short8 b1 = *(const short8*)(g + 512);
    short8 b2 = *(const short8*)(g + 1024);
    short8 b3 = *(const short8*)(g + 1536);
    accum(b0, b1, b2, b3, 512, labp[512 * 16 + col], nullptr, nullptr);
  }

  // row-side: reduce across the 16 column-lanes, one atomic per i-row
  // (waves own disjoint rows -> no cross-wave reduction needed)
#pragma unroll
  for (int it = 0; it < 2; ++it)
#pragma unroll
    for (int r = 0; r < 4; ++r) {
      float tt = stot[it][r], pp = spos[it][r];
#pragma unroll
      for (int m = 1; m <= 8; m <<= 1) {
        tt += __shfl_xor(tt, m);
        pp += __shfl_xor(pp, m);
      }
      if (col == 0) {
        int i = tix[it] * 16 + q * 4 + r;
        atomicAdd(&tot[i], tt);
        atomicAdd(&pos[i], pp);
      }
    }

  // col-side flush (redc complete after the loop's final __syncthreads)
  if (offdiag) {
    if (threadIdx.x < 128)
      atomicAdd(&tot[J * 128 + threadIdx.x], redc[threadIdx.x]);
    else
      atomicAdd(&pos[J * 128 + threadIdx.x - 128], redc[threadIdx.x]);
  }
}

// ---- loss kernel: loss = sum(lv * (lv>0.3)) / (sum(lv>0.3) + eps),
//      lv = -log( ((pos/(tot-9*epad))/(hist[lab]+eps)) + eps )
__global__ __launch_bounds__(1024)
void loss_kernel(const float* __restrict__ tot,
                 const float* __restrict__ pos,
                 const int* __restrict__ labels,
                 float* __restrict__ out) {
  __shared__ int hist[NUM_HIST];
  __shared__ float s1[16], s2[16];
  const int tid = threadIdx.x;
  const int lane = tid & 63, wid = tid >> 6;
  if (tid < NUM_HIST) hist[tid] = 0;
  __syncthreads();
  // ballot-based histogram: 7 ballots per 1024-element stripe, no LDS contention
  int c0 = 0, c1 = 0, c2 = 0, c3 = 0, c4 = 0, c5 = 0, c6 = 0;
  for (int i = tid; i < BN; i += 1024) {
    int lab = labels[i];
    unsigned long long m0 = __ballot(lab == 0);
    unsigned long long m1 = __ballot(lab == 1);
    unsigned long long m2 = __ballot(lab == 2);
    unsigned long long m3 = __ballot(lab == 3);
    unsigned long long m4 = __ballot(lab == 4);
    unsigned long long m5 = __ballot(lab == 5);
    unsigned long long m6 = __ballot(lab == 6);
    if (lane == 0) {
      c0 += __popcll(m0); c1 += __popcll(m1); c2 += __popcll(m2);
      c3 += __popcll(m3); c4 += __popcll(m4); c5 += __popcll(m5);
      c6 += __popcll(m6);
    }
  }
  if (lane == 0) {
    atomicAdd(&hist[0], c0); atomicAdd(&hist[1], c1); atomicAdd(&hist[2], c2);
    atomicAdd(&hist[3], c3); atomicAdd(&hist[4], c4); atomicAdd(&hist[5], c5);
    atomicAdd(&hist[6], c6);
  }
  __syncthreads();
  const float K2 = 10.30496147f;
  const float epad9 = 9.0f * exp2f(-K2);   // padded-column excess in tot
  float lsum = 0.f, msum = 0.f;
  for (int i = tid; i < BN; i += 1024) {
    float t = tot[i] - epad9;
    float p = pos[i];
    float c = (float)hist[labels[i]];   // = sum(pos_mask*mask) exactly
    float pr = (p / t) / (c + 1e-8f);
    float lv = -logf(pr + 1e-8f);
    if (lv > 0.3f) { lsum += lv; msum += 1.f; }
  }
#pragma unroll
  for (int m = 1; m < 64; m <<= 1) {
    lsum += __shfl_xor(lsum, m);
    msum += __shfl_xor(msum, m);
  }
  if (lane == 0) { s1[wid] = lsum; s2[wid] = msum; }
  __syncthreads();
  if (wid == 0) {
    float a = (lane < 16) ? s1[lane] : 0.f;
    float b = (lane < 16) ? s2[lane] : 0.f;
#pragma unroll
    for (int m = 1; m < 16; m <<= 1) {
      a += __shfl_xor(a, m);
      b += __shfl_xor(b, m);
    }
    if (lane == 0) out[0] = a / (b + 1e-8f);
  }
}

extern "C" void kernel_launch(void* const* d_in, const int* in_sizes, int n_in,
                              void* d_out, int out_size, void* d_ws, size_t ws_size,
                              hipStream_t stream) {
  const float* reps    = (const float*)d_in[0];  // [8192,128]
  const int*   labels  = (const int*)d_in[1];    // [8192]
  const float* centers = (const float*)d_in[2];  // [7,256]
  const float* fc_w    = (const float*)d_in[3];  // [128,256]
  const float* fc_b    = (const float*)d_in[4];  // [128]
  float* out = (float*)d_out;

  char* ws = (char*)d_ws;
  int* labp   = (int*)(ws + 4096);                       // 8208*4
  __hip_bfloat16* rnt = (__hip_bfloat16*)(ws + 40960);   // 513 tiles * 4KB = 2101248 B
  float* tot = (float*)(ws + 40960 + 2101248);           // 8192*4
  float* pos = tot + BN;                                 // 8192*4 (contiguous after tot)

  prep_kernel<<<2049, 256, 0, stream>>>(reps, labels, centers, fc_w, fc_b, rnt, labp, tot);
  main_kernel<<<NTRI, 256, 0, stream>>>(rnt, labp, tot, pos);
  loss_kernel<<<1, 1024, 0, stream>>>(tot, pos, labels, out);
}

// Round 13
// 145.532 us; speedup vs baseline: 1.2849x; 1.2849x over previous
//
#include <hip/hip_runtime.h>
#include <hip/hip_bf16.h>

#define BN 8192      // batch rows
#define MM 8199      // real rows (BN + 7 centers)
#define MP 8208      // padded to multiple of 16
#define HH 128       // feature dim
#define EE 256       // center embedding dim
#define TSUP 64      // 128-row super-tiles over the 8192 batch rows
#define NTRI 2080    // TSUP*(TSUP+1)/2 triangular blocks
#define NUM_HIST 7

typedef __attribute__((ext_vector_type(8))) short short8;   // 8 bf16 = 4 VGPRs
typedef __attribute__((ext_vector_type(4))) float floatx4;

// ============================================================================
// TRANSPOSED LAYOUT rnt (r7, measured -32%): MFMA-fragment order. Tile t
// (16 rows), k-block kblk (8 bf16), col: bf16 addr = t*2048 + kblk*128 + col*8.
// Fragment kk load = base + t*2048 + kk*512 + lane*8 -> contiguous 1KB/wave.
//
// r12 SYMMETRY HALVING (right idea, buggy impl): upper-triangle 128x128 blocks,
// row-sums to tot[i] AND col-sums to tot[j]; 67.2M -> 34.2M elements.
// r12 BUG (measured 89us, VGPR=64, WRITE +10MB): accum took `float* ct`
// selected at runtime (offdiag ? &ct : nullptr) -> pointer-to-local forced
// ct/cp into SCRATCH; every element did a scratch RMW (rule #20).
// r13 FIX: accum returns col-partials BY VALUE (float2, register-promoted);
// col sums computed unconditionally (2 VALU/elem extra on the 3% diag blocks),
// flushed only for offdiag. No pointers to locals anywhere.
// History: r1 (256,5)=spill; r3 __threadfence=L2 disaster; r4/r8 occupancy-null;
// r5 VALU-null; r6 pipeline-null; r9 LDS-share ~36us; r10 T14+pairs ~31us;
// r11 bigger-tile null (LDS port not binding).
// ============================================================================

// ---- prep kernel: fuses {zero tot/pos, centers GEMV, row-normalize+transpose}
__global__ __launch_bounds__(256)
void prep_kernel(const float* __restrict__ reps,
                 const int* __restrict__ labels,
                 const float* __restrict__ centers,
                 const float* __restrict__ fc_w,
                 const float* __restrict__ fc_b,
                 __hip_bfloat16* __restrict__ rnt,
                 int* __restrict__ labp,
                 float* __restrict__ tot) {  // pos = tot + BN (contiguous)
  const int wid = threadIdx.x >> 6, lane = threadIdx.x & 63;
  const int b = blockIdx.x;
  if (b < 2048) {
    if (threadIdx.x < 8) tot[b * 8 + threadIdx.x] = 0.f;   // zeroes tot+pos (16384 floats)
    const int r = b * 4 + wid;
    float2 v = ((const float2*)(reps + (size_t)r * HH))[lane];   // k = 2*lane, 2*lane+1
    float ss = v.x * v.x + v.y * v.y;
#pragma unroll
    for (int m = 1; m < 64; m <<= 1) ss += __shfl_xor(ss, m);
    float inv = 1.0f / fmaxf(sqrtf(ss), 1e-8f);
    __hip_bfloat162 h2;
    h2.x = __float2bfloat16(v.x * inv);
    h2.y = __float2bfloat16(v.y * inv);
    // transposed store: bf16 addr = (r>>4)*2048 + (lane>>2)*128 + (r&15)*8 + 2*(lane&3)
    size_t o = (size_t)(r >> 4) * 1024 + (lane >> 2) * 64 + (r & 15) * 4 + (lane & 3);
    ((__hip_bfloat162*)rnt)[o] = h2;
    if (lane == 0) labp[r] = labels[r];
  } else {
    // ---- block 2048: centers @ fc_w^T + fc_b  -> LDS, then padded rows
    __shared__ float currs[7 * HH];
    for (int o = threadIdx.x; o < 7 * HH; o += 256) {
      int c = o >> 7, h = o & 127;
      const float4* ce = (const float4*)(centers + c * EE);
      const float4* w  = (const float4*)(fc_w + h * EE);
      float s = 0.f;
#pragma unroll 4
      for (int j = 0; j < EE / 4; ++j) {
        float4 a = ce[j], bb = w[j];
        s += a.x * bb.x + a.y * bb.y + a.z * bb.z + a.w * bb.w;
      }
      currs[o] = s + fc_b[h];
    }
    __syncthreads();
    // rows 8192..8207 (j-tile 512): wave wid handles 4 rows; zeros for c>=7
    for (int k = 0; k < 4; ++k) {
      int c = wid * 4 + k;            // 0..15
      int r = BN + c;
      float2 v = make_float2(0.f, 0.f);
      if (c < 7) v = ((const float2*)(currs + c * HH))[lane];
      float ss = v.x * v.x + v.y * v.y;
#pragma unroll
      for (int m = 1; m < 64; m <<= 1) ss += __shfl_xor(ss, m);
      float inv = 1.0f / fmaxf(sqrtf(ss), 1e-8f);
      __hip_bfloat162 h2;
      h2.x = __float2bfloat16(v.x * inv);
      h2.y = __float2bfloat16(v.y * inv);
      size_t o = (size_t)(r >> 4) * 1024 + (lane >> 2) * 64 + (r & 15) * 4 + (lane & 3);
      ((__hip_bfloat162*)rnt)[o] = h2;
      if (lane == 0) labp[r] = (r < MM) ? r - BN : -1;
    }
  }
}

// ---- main kernel (triangular): block (I,J), I<=J, computes the 128x128 tile
// of e_ij = exp2((cos-1)*K2') for i in super-tile I, j in super-tile J.
// Row-sums -> tot/pos[i]; for I<J also col-sums -> tot/pos[j] (symmetry).
__global__ __launch_bounds__(256, 2)
void main_kernel(const __hip_bfloat16* __restrict__ rnt,
                 const int* __restrict__ labp,
                 float* __restrict__ tot,
                 float* __restrict__ pos) {
  __shared__ short lbuf[2][4096];    // double-buffered 8KB j-tile PAIR
  __shared__ float redc[256];        // [0..127] col tot, [128..255] col pos
  const int lane = threadIdx.x & 63;
  const int w    = threadIdx.x >> 6;
  const int q = lane >> 4, col = lane & 15;
  const short* rns = (const short*)rnt;

  // ---- decode triangular block index -> (I, J), J >= I
  // base(I) = I*TSUP - I*(I-1)/2 ; I via closed form + exact fixup
  const int idx = blockIdx.x;
  int I = (int)(64.5f - sqrtf(4160.25f - 2.0f * (float)idx));
  I = (I < 0) ? 0 : ((I > TSUP - 1) ? TSUP - 1 : I);
  while (I * TSUP - (I * (I - 1)) / 2 > idx) --I;
  while ((I + 1) * TSUP - ((I + 1) * I) / 2 <= idx) ++I;
  const int J = I + (idx - (I * TSUP - (I * (I - 1)) / 2));
  const bool offdiag = (I != J);

  redc[threadIdx.x] = 0.f;

  // A fragments: wave w owns i-tiles ti[it] = I*8 + w*2 + it (128 rows/block)
  short8 afrag[2][4];
  int tix[2];
#pragma unroll
  for (int it = 0; it < 2; ++it) {
    tix[it] = I * 8 + w * 2 + it;
    const short* base = rns + (size_t)tix[it] * 2048 + lane * 8;
    afrag[it][0] = *(const short8*)(base);
    afrag[it][1] = *(const short8*)(base + 512);
    afrag[it][2] = *(const short8*)(base + 1024);
    afrag[it][3] = *(const short8*)(base + 1536);
  }
  int labi[2][4];
#pragma unroll
  for (int it = 0; it < 2; ++it)
#pragma unroll
    for (int r = 0; r < 4; ++r)
      labi[it][r] = labp[tix[it] * 16 + q * 4 + r];

  float stot[2][4] = {};
  float spos[2][4] = {};
  const float K2 = 10.30496147f;  // 0.5/0.07 * log2(e)

  // accumulate one j-tile; row sums into captured stot/spos (registers);
  // col partials returned BY VALUE (register-promoted — never via pointer,
  // r12's pointer-to-local forced scratch and tripled runtime).
  auto accum = [&](short8 b0, short8 b1, short8 b2, short8 b3,
                   int t, int labj) -> float2 {
    float ct = 0.f, cp = 0.f;
#pragma unroll
    for (int it = 0; it < 2; ++it) {
      floatx4 acc = {0.f, 0.f, 0.f, 0.f};
      acc = __builtin_amdgcn_mfma_f32_16x16x32_bf16(afrag[it][0], b0, acc, 0, 0, 0);
      acc = __builtin_amdgcn_mfma_f32_16x16x32_bf16(afrag[it][1], b1, acc, 0, 0, 0);
      acc = __builtin_amdgcn_mfma_f32_16x16x32_bf16(afrag[it][2], b2, acc, 0, 0, 0);
      acc = __builtin_amdgcn_mfma_f32_16x16x32_bf16(afrag[it][3], b3, acc, 0, 0, 0);
      float ev[4];
#pragma unroll
      for (int r = 0; r < 4; ++r) {
        // C/D layout: row = q*4+r, col = lane&15 -> i = tix*16+q*4+r, j = t*16+col
        float e = __builtin_amdgcn_exp2f(fmaf(acc[r], K2, -K2));  // raw v_exp_f32
        ev[r] = e;
        float m = (labj == labi[it][r]) ? e : 0.f;
        stot[it][r] += e;
        spos[it][r] += m;
        ct += e;
        cp += m;
      }
      if (t == tix[it]) {          // wave-uniform diagonal fix-up (I==J only)
#pragma unroll
        for (int r = 0; r < 4; ++r)
          if (col == q * 4 + r) { stot[it][r] -= ev[r]; spos[it][r] -= ev[r]; }
      }
    }
    return make_float2(ct, cp);
  };

  const int t0 = J * 8;   // 8 j-tiles per block

  // prologue: stage pair 0 (each thread 2x16B, coalesced)
  {
    const short* g = rns + (size_t)t0 * 2048 + threadIdx.x * 8;
    *(short8*)&lbuf[0][threadIdx.x * 8] = *(const short8*)g;
    *(short8*)&lbuf[0][2048 + threadIdx.x * 8] = *(const short8*)(g + 2048);
  }
  __syncthreads();

  for (int p = 0; p < 4; ++p) {
    const int cur = p & 1;
    const int t = t0 + p * 2;
    // T14 split: issue next pair's loads into regs NOW, ds_write after compute
    short8 nv0, nv1;
    const bool more = (p < 3);
    if (more) {
      const short* g = rns + (size_t)(t + 2) * 2048 + threadIdx.x * 8;
      nv0 = *(const short8*)g;
      nv1 = *(const short8*)(g + 2048);
    }
    const int labj0 = labp[t * 16 + col];
    const int labj1 = labp[t * 16 + 16 + col];

    const short* lb = &lbuf[cur][0];
#pragma unroll
    for (int u = 0; u < 2; ++u) {           // two tiles in the staged pair
      const short* s = lb + u * 2048;
      short8 b0 = *(const short8*)(s + lane * 8);
      short8 b1 = *(const short8*)(s + 512 + lane * 8);
      short8 b2 = *(const short8*)(s + 1024 + lane * 8);
      short8 b3 = *(const short8*)(s + 1536 + lane * 8);
      float2 c2 = accum(b0, b1, b2, b3, t + u, u ? labj1 : labj0);
      if (offdiag) {
        // col sums: reduce across the 4 q-groups (lanes col, col+16, +32, +48)
        float ct = c2.x, cp = c2.y;
        ct += __shfl_xor(ct, 16); ct += __shfl_xor(ct, 32);
        cp += __shfl_xor(cp, 16); cp += __shfl_xor(cp, 32);
        if (q == 0) {
          int cj = (p * 2 + u) * 16 + col;        // 0..127 within J super-tile
          atomicAdd(&redc[cj], ct);
          atomicAdd(&redc[128 + cj], cp);
        }
      }
    }

    if (more) {   // vmcnt wait lands HERE, after the pair's compute
      *(short8*)&lbuf[cur ^ 1][threadIdx.x * 8] = nv0;
      *(short8*)&lbuf[cur ^ 1][2048 + threadIdx.x * 8] = nv1;
    }
    __syncthreads();
  }

  // diag blocks own the centers strip (tile 512, rows 8192..8207, row-side only)
  if (!offdiag) {
    const short* g = rns + (size_t)512 * 2048 + lane * 8;
    short8 b0 = *(const short8*)(g);
    short8 b1 = *(const short8*)(g + 512);
    short8 b2 = *(const short8*)(g + 1024);
    short8 b3 = *(const short8*)(g + 1536);
    (void)accum(b0, b1, b2, b3, 512, labp[512 * 16 + col]);
  }

  // row-side: reduce across the 16 column-lanes, one atomic per i-row
  // (waves own disjoint rows -> no cross-wave reduction needed)
#pragma unroll
  for (int it = 0; it < 2; ++it)
#pragma unroll
    for (int r = 0; r < 4; ++r) {
      float tt = stot[it][r], pp = spos[it][r];
#pragma unroll
      for (int m = 1; m <= 8; m <<= 1) {
        tt += __shfl_xor(tt, m);
        pp += __shfl_xor(pp, m);
      }
      if (col == 0) {
        int i = tix[it] * 16 + q * 4 + r;
        atomicAdd(&tot[i], tt);
        atomicAdd(&pos[i], pp);
      }
    }

  // col-side flush (redc complete after the loop's final __syncthreads)
  if (offdiag) {
    if (threadIdx.x < 128)
      atomicAdd(&tot[J * 128 + threadIdx.x], redc[threadIdx.x]);
    else
      atomicAdd(&pos[J * 128 + threadIdx.x - 128], redc[threadIdx.x]);
  }
}

// ---- loss kernel: loss = sum(lv * (lv>0.3)) / (sum(lv>0.3) + eps),
//      lv = -log( ((pos/(tot-9*epad))/(hist[lab]+eps)) + eps )
__global__ __launch_bounds__(1024)
void loss_kernel(const float* __restrict__ tot,
                 const float* __restrict__ pos,
                 const int* __restrict__ labels,
                 float* __restrict__ out) {
  __shared__ int hist[NUM_HIST];
  __shared__ float s1[16], s2[16];
  const int tid = threadIdx.x;
  const int lane = tid & 63, wid = tid >> 6;
  if (tid < NUM_HIST) hist[tid] = 0;
  __syncthreads();
  // ballot-based histogram: 7 ballots per 1024-element stripe, no LDS contention
  int c0 = 0, c1 = 0, c2 = 0, c3 = 0, c4 = 0, c5 = 0, c6 = 0;
  for (int i = tid; i < BN; i += 1024) {
    int lab = labels[i];
    unsigned long long m0 = __ballot(lab == 0);
    unsigned long long m1 = __ballot(lab == 1);
    unsigned long long m2 = __ballot(lab == 2);
    unsigned long long m3 = __ballot(lab == 3);
    unsigned long long m4 = __ballot(lab == 4);
    unsigned long long m5 = __ballot(lab == 5);
    unsigned long long m6 = __ballot(lab == 6);
    if (lane == 0) {
      c0 += __popcll(m0); c1 += __popcll(m1); c2 += __popcll(m2);
      c3 += __popcll(m3); c4 += __popcll(m4); c5 += __popcll(m5);
      c6 += __popcll(m6);
    }
  }
  if (lane == 0) {
    atomicAdd(&hist[0], c0); atomicAdd(&hist[1], c1); atomicAdd(&hist[2], c2);
    atomicAdd(&hist[3], c3); atomicAdd(&hist[4], c4); atomicAdd(&hist[5], c5);
    atomicAdd(&hist[6], c6);
  }
  __syncthreads();
  const float K2 = 10.30496147f;
  const float epad9 = 9.0f * exp2f(-K2);   // padded-column excess in tot
  float lsum = 0.f, msum = 0.f;
  for (int i = tid; i < BN; i += 1024) {
    float t = tot[i] - epad9;
    float p = pos[i];
    float c = (float)hist[labels[i]];   // = sum(pos_mask*mask) exactly
    float pr = (p / t) / (c + 1e-8f);
    float lv = -logf(pr + 1e-8f);
    if (lv > 0.3f) { lsum += lv; msum += 1.f; }
  }
#pragma unroll
  for (int m = 1; m < 64; m <<= 1) {
    lsum += __shfl_xor(lsum, m);
    msum += __shfl_xor(msum, m);
  }
  if (lane == 0) { s1[wid] = lsum; s2[wid] = msum; }
  __syncthreads();
  if (wid == 0) {
    float a = (lane < 16) ? s1[lane] : 0.f;
    float b = (lane < 16) ? s2[lane] : 0.f;
#pragma unroll
    for (int m = 1; m < 16; m <<= 1) {
      a += __shfl_xor(a, m);
      b += __shfl_xor(b, m);
    }
    if (lane == 0) out[0] = a / (b + 1e-8f);
  }
}

extern "C" void kernel_launch(void* const* d_in, const int* in_sizes, int n_in,
                              void* d_out, int out_size, void* d_ws, size_t ws_size,
                              hipStream_t stream) {
  const float* reps    = (const float*)d_in[0];  // [8192,128]
  const int*   labels  = (const int*)d_in[1];    // [8192]
  const float* centers = (const float*)d_in[2];  // [7,256]
  const float* fc_w    = (const float*)d_in[3];  // [128,256]
  const float* fc_b    = (const float*)d_in[4];  // [128]
  float* out = (float*)d_out;

  char* ws = (char*)d_ws;
  int* labp   = (int*)(ws + 4096);                       // 8208*4
  __hip_bfloat16* rnt = (__hip_bfloat16*)(ws + 40960);   // 513 tiles * 4KB = 2101248 B
  float* tot = (float*)(ws + 40960 + 2101248);           // 8192*4
  float* pos = tot + BN;                                 // 8192*4 (contiguous after tot)

  prep_kernel<<<2049, 256, 0, stream>>>(reps, labels, centers, fc_w, fc_b, rnt, labp, tot);
  main_kernel<<<NTRI, 256, 0, stream>>>(rnt, labp, tot, pos);
  loss_kernel<<<1, 1024, 0, stream>>>(tot, pos, labels, out);
}

// Round 14
// 139.577 us; speedup vs baseline: 1.3398x; 1.0427x over previous
//
#include <hip/hip_runtime.h>
#include <hip/hip_bf16.h>

#define BN 8192      // batch rows
#define MM 8199      // real rows (BN + 7 centers)
#define MP 8208      // padded to multiple of 16
#define HH 128       // feature dim
#define EE 256       // center embedding dim
#define NBLK14 1056  // rectangular-triangular blocks: sum over x of (32 - x/2)
#define NUM_HIST 7

typedef __attribute__((ext_vector_type(8))) short short8;   // 8 bf16 = 4 VGPRs
typedef __attribute__((ext_vector_type(4))) float floatx4;

// ============================================================================
// TRANSPOSED LAYOUT rnt (r7, measured -32%): MFMA-fragment order. Tile t
// (16 rows), k-block kblk (8 bf16), col: bf16 addr = t*2048 + kblk*128 + col*8.
// Fragment kk load = base + t*2048 + kk*512 + lane*8 -> contiguous 1KB/wave.
//
// SYMMETRY (r12-r14): e_ij = e_ji and the label-match is symmetric -> compute
// each unordered pair once, scatter row-sums to tot[i] and col-sums to tot[j].
// r13 lesson (44us, worse than r10's 31us at 2x elements): 128x128 blocks
// amortized per-block fixed costs over only 8 j-tiles. r14: 128 i-rows x
// 256 j-cols rectangles, block (x,y) exists iff y >= x>>1 (1056 blocks,
// 16 j-tiles each = r10's staging depth halved, 4.1 blocks/CU):
//  - y > x>>1: row-sums + col-sums (transposed pair covered by col-scatter)
//  - y == x>>1: row-sums ONLY over the full 256 cols (both orders of
//    same-chunk pairs come from their own strips' row-sums; no double count);
//    these 64 blocks also do the diag fixup and the centers strip (tile 512).
// Coverage: every ordered (i,j), i!=j, lands exactly once. Audited.
// History: r1 (256,5)=spill; r3 __threadfence=L2 disaster; r4/r8 occupancy-
// null; r5 VALU-null; r6 pipeline-null; r7 coalesce -32%; r9 LDS-share;
// r10 T14+pairs ~31us; r11 bigger-tile null; r12 pointer-to-local scratch.
// ============================================================================

// ---- prep kernel: fuses {zero tot/pos, centers GEMV, row-normalize+transpose}
__global__ __launch_bounds__(256)
void prep_kernel(const float* __restrict__ reps,
                 const int* __restrict__ labels,
                 const float* __restrict__ centers,
                 const float* __restrict__ fc_w,
                 const float* __restrict__ fc_b,
                 __hip_bfloat16* __restrict__ rnt,
                 int* __restrict__ labp,
                 float* __restrict__ tot) {  // pos = tot + BN (contiguous)
  const int wid = threadIdx.x >> 6, lane = threadIdx.x & 63;
  const int b = blockIdx.x;
  if (b < 2048) {
    if (threadIdx.x < 8) tot[b * 8 + threadIdx.x] = 0.f;   // zeroes tot+pos (16384 floats)
    const int r = b * 4 + wid;
    float2 v = ((const float2*)(reps + (size_t)r * HH))[lane];   // k = 2*lane, 2*lane+1
    float ss = v.x * v.x + v.y * v.y;
#pragma unroll
    for (int m = 1; m < 64; m <<= 1) ss += __shfl_xor(ss, m);
    float inv = 1.0f / fmaxf(sqrtf(ss), 1e-8f);
    __hip_bfloat162 h2;
    h2.x = __float2bfloat16(v.x * inv);
    h2.y = __float2bfloat16(v.y * inv);
    // transposed store: bf16 addr = (r>>4)*2048 + (lane>>2)*128 + (r&15)*8 + 2*(lane&3)
    size_t o = (size_t)(r >> 4) * 1024 + (lane >> 2) * 64 + (r & 15) * 4 + (lane & 3);
    ((__hip_bfloat162*)rnt)[o] = h2;
    if (lane == 0) labp[r] = labels[r];
  } else {
    // ---- block 2048: centers @ fc_w^T + fc_b  -> LDS, then padded rows
    __shared__ float currs[7 * HH];
    for (int o = threadIdx.x; o < 7 * HH; o += 256) {
      int c = o >> 7, h = o & 127;
      const float4* ce = (const float4*)(centers + c * EE);
      const float4* w  = (const float4*)(fc_w + h * EE);
      float s = 0.f;
#pragma unroll 4
      for (int j = 0; j < EE / 4; ++j) {
        float4 a = ce[j], bb = w[j];
        s += a.x * bb.x + a.y * bb.y + a.z * bb.z + a.w * bb.w;
      }
      currs[o] = s + fc_b[h];
    }
    __syncthreads();
    // rows 8192..8207 (j-tile 512): wave wid handles 4 rows; zeros for c>=7
    for (int k = 0; k < 4; ++k) {
      int c = wid * 4 + k;            // 0..15
      int r = BN + c;
      float2 v = make_float2(0.f, 0.f);
      if (c < 7) v = ((const float2*)(currs + c * HH))[lane];
      float ss = v.x * v.x + v.y * v.y;
#pragma unroll
      for (int m = 1; m < 64; m <<= 1) ss += __shfl_xor(ss, m);
      float inv = 1.0f / fmaxf(sqrtf(ss), 1e-8f);
      __hip_bfloat162 h2;
      h2.x = __float2bfloat16(v.x * inv);
      h2.y = __float2bfloat16(v.y * inv);
      size_t o = (size_t)(r >> 4) * 1024 + (lane >> 2) * 64 + (r & 15) * 4 + (lane & 3);
      ((__hip_bfloat162*)rnt)[o] = h2;
      if (lane == 0) labp[r] = (r < MM) ? r - BN : -1;
    }
  }
}

// ---- main kernel: block (x,y): i-strip x (128 rows), j-chunk y (256 cols).
// Row-sums -> tot/pos[i]; for y > x>>1 also col-sums -> tot/pos[j] (symmetry).
__global__ __launch_bounds__(256, 2)
void main_kernel(const __hip_bfloat16* __restrict__ rnt,
                 const int* __restrict__ labp,
                 float* __restrict__ tot,
                 float* __restrict__ pos) {
  __shared__ short lbuf[2][4096];    // double-buffered 8KB j-tile PAIR
  __shared__ float redc[512];        // [0..255] col tot, [256..511] col pos
  const int lane = threadIdx.x & 63;
  const int w    = threadIdx.x >> 6;
  const int q = lane >> 4, col = lane & 15;
  const short* rns = (const short*)rnt;

  // ---- decode block index -> (x, y): count per strip x is 32 - (x>>1)
  int x = 0, rem = blockIdx.x;
  while (rem >= 32 - (x >> 1)) { rem -= 32 - (x >> 1); ++x; }
  const int y = (x >> 1) + rem;
  const bool offdiag = (rem > 0);    // y > x>>1

  redc[threadIdx.x] = 0.f;
  redc[256 + threadIdx.x] = 0.f;

  // A fragments: wave w owns i-tiles tix[it] = x*8 + w*2 + it
  short8 afrag[2][4];
  int tix[2];
#pragma unroll
  for (int it = 0; it < 2; ++it) {
    tix[it] = x * 8 + w * 2 + it;
    const short* base = rns + (size_t)tix[it] * 2048 + lane * 8;
    afrag[it][0] = *(const short8*)(base);
    afrag[it][1] = *(const short8*)(base + 512);
    afrag[it][2] = *(const short8*)(base + 1024);
    afrag[it][3] = *(const short8*)(base + 1536);
  }
  int labi[2][4];
#pragma unroll
  for (int it = 0; it < 2; ++it)
#pragma unroll
    for (int r = 0; r < 4; ++r)
      labi[it][r] = labp[tix[it] * 16 + q * 4 + r];

  float stot[2][4] = {};
  float spos[2][4] = {};
  const float K2 = 10.30496147f;  // 0.5/0.07 * log2(e)

  // accumulate one j-tile; row sums into captured stot/spos (registers);
  // col partials returned BY VALUE (rule #20: never via pointer-to-local).
  auto accum = [&](short8 b0, short8 b1, short8 b2, short8 b3,
                   int t, int labj) -> float2 {
    float ct = 0.f, cp = 0.f;
#pragma unroll
    for (int it = 0; it < 2; ++it) {
      floatx4 acc = {0.f, 0.f, 0.f, 0.f};
      acc = __builtin_amdgcn_mfma_f32_16x16x32_bf16(afrag[it][0], b0, acc, 0, 0, 0);
      acc = __builtin_amdgcn_mfma_f32_16x16x32_bf16(afrag[it][1], b1, acc, 0, 0, 0);
      acc = __builtin_amdgcn_mfma_f32_16x16x32_bf16(afrag[it][2], b2, acc, 0, 0, 0);
      acc = __builtin_amdgcn_mfma_f32_16x16x32_bf16(afrag[it][3], b3, acc, 0, 0, 0);
      float ev[4];
#pragma unroll
      for (int r = 0; r < 4; ++r) {
        // C/D layout: row = q*4+r, col = lane&15 -> i = tix*16+q*4+r, j = t*16+col
        float e = __builtin_amdgcn_exp2f(fmaf(acc[r], K2, -K2));  // raw v_exp_f32
        ev[r] = e;
        float m = (labj == labi[it][r]) ? e : 0.f;
        stot[it][r] += e;
        spos[it][r] += m;
        ct += e;
        cp += m;
      }
      if (t == tix[it]) {          // wave-uniform diagonal fix-up (y==x>>1 only)
#pragma unroll
        for (int r = 0; r < 4; ++r)
          if (col == q * 4 + r) { stot[it][r] -= ev[r]; spos[it][r] -= ev[r]; }
      }
    }
    return make_float2(ct, cp);
  };

  const int t0 = y * 16;   // 16 j-tiles per block (256 cols)

  // prologue: stage pair 0 (each thread 2x16B, coalesced)
  {
    const short* g = rns + (size_t)t0 * 2048 + threadIdx.x * 8;
    *(short8*)&lbuf[0][threadIdx.x * 8] = *(const short8*)g;
    *(short8*)&lbuf[0][2048 + threadIdx.x * 8] = *(const short8*)(g + 2048);
  }
  __syncthreads();

  for (int p = 0; p < 8; ++p) {
    const int cur = p & 1;
    const int t = t0 + p * 2;
    // T14 split: issue next pair's loads into regs NOW, ds_write after compute
    short8 nv0, nv1;
    const bool more = (p < 7);
    if (more) {
      const short* g = rns + (size_t)(t + 2) * 2048 + threadIdx.x * 8;
      nv0 = *(const short8*)g;
      nv1 = *(const short8*)(g + 2048);
    }
    const int labj0 = labp[t * 16 + col];
    const int labj1 = labp[t * 16 + 16 + col];

    const short* lb = &lbuf[cur][0];
#pragma unroll
    for (int u = 0; u < 2; ++u) {           // two tiles in the staged pair
      const short* s = lb + u * 2048;
      short8 b0 = *(const short8*)(s + lane * 8);
      short8 b1 = *(const short8*)(s + 512 + lane * 8);
      short8 b2 = *(const short8*)(s + 1024 + lane * 8);
      short8 b3 = *(const short8*)(s + 1536 + lane * 8);
      float2 c2 = accum(b0, b1, b2, b3, t + u, u ? labj1 : labj0);
      if (offdiag) {
        // col sums: reduce across the 4 q-groups (lanes col, col+16, +32, +48)
        float ct = c2.x, cp = c2.y;
        ct += __shfl_xor(ct, 16); ct += __shfl_xor(ct, 32);
        cp += __shfl_xor(cp, 16); cp += __shfl_xor(cp, 32);
        if (q == 0) {
          int cj = (p * 2 + u) * 16 + col;        // 0..255 within j-chunk y
          atomicAdd(&redc[cj], ct);
          atomicAdd(&redc[256 + cj], cp);
        }
      }
    }

    if (more) {   // vmcnt wait lands HERE, after the pair's compute
      *(short8*)&lbuf[cur ^ 1][threadIdx.x * 8] = nv0;
      *(short8*)&lbuf[cur ^ 1][2048 + threadIdx.x * 8] = nv1;
    }
    __syncthreads();
  }

  // y==x>>1 blocks own the centers strip (tile 512, rows 8192..8207, row-only)
  if (!offdiag) {
    const short* g = rns + (size_t)512 * 2048 + lane * 8;
    short8 b0 = *(const short8*)(g);
    short8 b1 = *(const short8*)(g + 512);
    short8 b2 = *(const short8*)(g + 1024);
    short8 b3 = *(const short8*)(g + 1536);
    (void)accum(b0, b1, b2, b3, 512, labp[512 * 16 + col]);
  }

  // row-side: reduce across the 16 column-lanes, one atomic per i-row
  // (waves own disjoint rows -> no cross-wave reduction needed)
#pragma unroll
  for (int it = 0; it < 2; ++it)
#pragma unroll
    for (int r = 0; r < 4; ++r) {
      float tt = stot[it][r], pp = spos[it][r];
#pragma unroll
      for (int m = 1; m <= 8; m <<= 1) {
        tt += __shfl_xor(tt, m);
        pp += __shfl_xor(pp, m);
      }
      if (col == 0) {
        int i = tix[it] * 16 + q * 4 + r;
        atomicAdd(&tot[i], tt);
        atomicAdd(&pos[i], pp);
      }
    }

  // col-side flush (redc complete after the loop's final __syncthreads)
  if (offdiag) {
    atomicAdd(&tot[y * 256 + threadIdx.x], redc[threadIdx.x]);
    atomicAdd(&pos[y * 256 + threadIdx.x], redc[256 + threadIdx.x]);
  }
}

// ---- loss kernel: loss = sum(lv * (lv>0.3)) / (sum(lv>0.3) + eps),
//      lv = -log( ((pos/(tot-9*epad))/(hist[lab]+eps)) + eps )
__global__ __launch_bounds__(1024)
void loss_kernel(const float* __restrict__ tot,
                 const float* __restrict__ pos,
                 const int* __restrict__ labels,
                 float* __restrict__ out) {
  __shared__ int hist[NUM_HIST];
  __shared__ float s1[16], s2[16];
  const int tid = threadIdx.x;
  const int lane = tid & 63, wid = tid >> 6;
  if (tid < NUM_HIST) hist[tid] = 0;
  __syncthreads();
  // ballot-based histogram: 7 ballots per 1024-element stripe, no LDS contention
  int c0 = 0, c1 = 0, c2 = 0, c3 = 0, c4 = 0, c5 = 0, c6 = 0;
  for (int i = tid; i < BN; i += 1024) {
    int lab = labels[i];
    unsigned long long m0 = __ballot(lab == 0);
    unsigned long long m1 = __ballot(lab == 1);
    unsigned long long m2 = __ballot(lab == 2);
    unsigned long long m3 = __ballot(lab == 3);
    unsigned long long m4 = __ballot(lab == 4);
    unsigned long long m5 = __ballot(lab == 5);
    unsigned long long m6 = __ballot(lab == 6);
    if (lane == 0) {
      c0 += __popcll(m0); c1 += __popcll(m1); c2 += __popcll(m2);
      c3 += __popcll(m3); c4 += __popcll(m4); c5 += __popcll(m5);
      c6 += __popcll(m6);
    }
  }
  if (lane == 0) {
    atomicAdd(&hist[0], c0); atomicAdd(&hist[1], c1); atomicAdd(&hist[2], c2);
    atomicAdd(&hist[3], c3); atomicAdd(&hist[4], c4); atomicAdd(&hist[5], c5);
    atomicAdd(&hist[6], c6);
  }
  __syncthreads();
  const float K2 = 10.30496147f;
  const float epad9 = 9.0f * exp2f(-K2);   // padded-column excess in tot
  float lsum = 0.f, msum = 0.f;
  for (int i = tid; i < BN; i += 1024) {
    float t = tot[i] - epad9;
    float p = pos[i];
    float c = (float)hist[labels[i]];   // = sum(pos_mask*mask) exactly
    float pr = (p / t) / (c + 1e-8f);
    float lv = -logf(pr + 1e-8f);
    if (lv > 0.3f) { lsum += lv; msum += 1.f; }
  }
#pragma unroll
  for (int m = 1; m < 64; m <<= 1) {
    lsum += __shfl_xor(lsum, m);
    msum += __shfl_xor(msum, m);
  }
  if (lane == 0) { s1[wid] = lsum; s2[wid] = msum; }
  __syncthreads();
  if (wid == 0) {
    float a = (lane < 16) ? s1[lane] : 0.f;
    float b = (lane < 16) ? s2[lane] : 0.f;
#pragma unroll
    for (int m = 1; m < 16; m <<= 1) {
      a += __shfl_xor(a, m);
      b += __shfl_xor(b, m);
    }
    if (lane == 0) out[0] = a / (b + 1e-8f);
  }
}

extern "C" void kernel_launch(void* const* d_in, const int* in_sizes, int n_in,
                              void* d_out, int out_size, void* d_ws, size_t ws_size,
                              hipStream_t stream) {
  const float* reps    = (const float*)d_in[0];  // [8192,128]
  const int*   labels  = (const int*)d_in[1];    // [8192]
  const float* centers = (const float*)d_in[2];  // [7,256]
  const float* fc_w    = (const float*)d_in[3];  // [128,256]
  const float* fc_b    = (const float*)d_in[4];  // [128]
  float* out = (float*)d_out;

  char* ws = (char*)d_ws;
  int* labp   = (int*)(ws + 4096);                       // 8208*4
  __hip_bfloat16* rnt = (__hip_bfloat16*)(ws + 40960);   // 513 tiles * 4KB = 2101248 B
  float* tot = (float*)(ws + 40960 + 2101248);           // 8192*4
  float* pos = tot + BN;                                 // 8192*4 (contiguous after tot)

  prep_kernel<<<2049, 256, 0, stream>>>(reps, labels, centers, fc_w, fc_b, rnt, labp, tot);
  main_kernel<<<NBLK14, 256, 0, stream>>>(rnt, labp, tot, pos);
  loss_kernel<<<1, 1024, 0, stream>>>(tot, pos, labels, out);
}

// Round 15
// 129.530 us; speedup vs baseline: 1.4437x; 1.0776x over previous
//
#include <hip/hip_runtime.h>
#include <hip/hip_bf16.h>

#define BN 8192      // batch rows
#define MM 8199      // real rows (BN + 7 centers)
#define MP 8208      // padded to multiple of 16
#define HH 128       // feature dim
#define EE 256       // center embedding dim
#define GX2 64       // i-blocks (128 rows each)
#define GY 16        // j-chunks (32 tiles each; y=15 also does padded tile 512)
#define NUM_HIST 7

typedef __attribute__((ext_vector_type(8))) short short8;   // 8 bf16 = 4 VGPRs
typedef __attribute__((ext_vector_type(4))) float floatx4;

// ============================================================================
// TRANSPOSED LAYOUT rnt (r7, measured -32%): MFMA-fragment order. Tile t
// (16 rows), k-block kblk (8 bf16), col: bf16 addr = t*2048 + kblk*128 + col*8.
// Fragment kk load = base + t*2048 + kk*512 + lane*8 -> contiguous 1KB/wave.
//
// r10 anchor (best measured: total 131.1, main ~31us): 128 i-rows/block, waves
// split i (afrag[2][4]), B shared via LDS, T14 stage split (loads->regs before
// compute, ds_write after), 2 tiles/barrier, wave-uniform diag hoist.
// r15: QUAD staging — 4 tiles per barrier (2x16KB LDS buffers, 8 sync points
// vs 16). r13 counters (same family) showed all pipes <30% with sync/drain as
// the residual; halving barrier count amortizes the drain 2x.
// SYMMETRY REVERTED: r12 (pointer-to-local scratch, 89us), r13 (128x128 poor
// amortization, 44us), r14 (128x256 rect-tri, ~39us) all lost to r10's plain
// full-matrix 31us — fixed per-block costs + col-sum epilogue + lost L2
// streaming locality eat the halved element count at feasible tile sizes.
// History: r1 (256,5)=spill; r3 __threadfence=L2 disaster; r4/r8 occupancy-
// null; r5 VALU-null; r6 pipeline-null (pre-coalescing); r11 bigger-tile null.
// ============================================================================

// ---- prep kernel: fuses {zero tot/pos, centers GEMV, row-normalize+transpose}
__global__ __launch_bounds__(256)
void prep_kernel(const float* __restrict__ reps,
                 const int* __restrict__ labels,
                 const float* __restrict__ centers,
                 const float* __restrict__ fc_w,
                 const float* __restrict__ fc_b,
                 __hip_bfloat16* __restrict__ rnt,
                 int* __restrict__ labp,
                 float* __restrict__ tot) {  // pos = tot + BN (contiguous)
  const int wid = threadIdx.x >> 6, lane = threadIdx.x & 63;
  const int b = blockIdx.x;
  if (b < 2048) {
    if (threadIdx.x < 8) tot[b * 8 + threadIdx.x] = 0.f;   // zeroes tot+pos (16384 floats)
    const int r = b * 4 + wid;
    float2 v = ((const float2*)(reps + (size_t)r * HH))[lane];   // k = 2*lane, 2*lane+1
    float ss = v.x * v.x + v.y * v.y;
#pragma unroll
    for (int m = 1; m < 64; m <<= 1) ss += __shfl_xor(ss, m);
    float inv = 1.0f / fmaxf(sqrtf(ss), 1e-8f);
    __hip_bfloat162 h2;
    h2.x = __float2bfloat16(v.x * inv);
    h2.y = __float2bfloat16(v.y * inv);
    // transposed store: bf16 addr = (r>>4)*2048 + (lane>>2)*128 + (r&15)*8 + 2*(lane&3)
    size_t o = (size_t)(r >> 4) * 1024 + (lane >> 2) * 64 + (r & 15) * 4 + (lane & 3);
    ((__hip_bfloat162*)rnt)[o] = h2;
    if (lane == 0) labp[r] = labels[r];
  } else {
    // ---- block 2048: centers @ fc_w^T + fc_b  -> LDS, then padded rows
    __shared__ float currs[7 * HH];
    for (int o = threadIdx.x; o < 7 * HH; o += 256) {
      int c = o >> 7, h = o & 127;
      const float4* ce = (const float4*)(centers + c * EE);
      const float4* w  = (const float4*)(fc_w + h * EE);
      float s = 0.f;
#pragma unroll 4
      for (int j = 0; j < EE / 4; ++j) {
        float4 a = ce[j], bb = w[j];
        s += a.x * bb.x + a.y * bb.y + a.z * bb.z + a.w * bb.w;
      }
      currs[o] = s + fc_b[h];
    }
    __syncthreads();
    // rows 8192..8207 (j-tile 512): wave wid handles 4 rows; zeros for c>=7
    for (int k = 0; k < 4; ++k) {
      int c = wid * 4 + k;            // 0..15
      int r = BN + c;
      float2 v = make_float2(0.f, 0.f);
      if (c < 7) v = ((const float2*)(currs + c * HH))[lane];
      float ss = v.x * v.x + v.y * v.y;
#pragma unroll
      for (int m = 1; m < 64; m <<= 1) ss += __shfl_xor(ss, m);
      float inv = 1.0f / fmaxf(sqrtf(ss), 1e-8f);
      __hip_bfloat162 h2;
      h2.x = __float2bfloat16(v.x * inv);
      h2.y = __float2bfloat16(v.y * inv);
      size_t o = (size_t)(r >> 4) * 1024 + (lane >> 2) * 64 + (r & 15) * 4 + (lane & 3);
      ((__hip_bfloat162*)rnt)[o] = h2;
      if (lane == 0) labp[r] = (r < MM) ? r - BN : -1;
    }
  }
}

// ---- main kernel: per i-row, tot_i = sum_j e_ij (j!=i), pos_i = same over label match
// e_ij = exp2((cos_ij - 1) * (0.5/TEMP) * log2e)   [global-max shift cancels in ratio]
// Padded j-columns (rnt==0) contribute exactly exp2(-K2) each to tot; the loss
// kernel subtracts the exact constant 9*exp2(-K2). Padded labp=-1 never matches.
__global__ __launch_bounds__(256, 2)
void main_kernel(const __hip_bfloat16* __restrict__ rnt,
                 const int* __restrict__ labp,
                 float* __restrict__ tot,
                 float* __restrict__ pos) {
  __shared__ short lbuf[2][8192];    // double-buffered 16KB tile-QUAD
  const int lane = threadIdx.x & 63;
  const int w    = threadIdx.x >> 6;       // wave id: owns i-rows [w*32, w*32+32)
  const int q = lane >> 4, col = lane & 15;
  const int ibase = blockIdx.x * 128;
  const short* rns = (const short*)rnt;

  // A fragments for this wave's two i-tiles: Ti = bx*8 + w*2 + it
  short8 afrag[2][4];
  int tix[2];
#pragma unroll
  for (int it = 0; it < 2; ++it) {
    tix[it] = blockIdx.x * 8 + w * 2 + it;
    const short* base = rns + (size_t)tix[it] * 2048 + lane * 8;
    afrag[it][0] = *(const short8*)(base);
    afrag[it][1] = *(const short8*)(base + 512);
    afrag[it][2] = *(const short8*)(base + 1024);
    afrag[it][3] = *(const short8*)(base + 1536);
  }
  // i-labels for C/D layout rows: row = q*4 + r
  int labi[2][4];
#pragma unroll
  for (int it = 0; it < 2; ++it)
#pragma unroll
    for (int r = 0; r < 4; ++r)
      labi[it][r] = labp[ibase + (w * 2 + it) * 16 + q * 4 + r];

  float stot[2][4] = {};
  float spos[2][4] = {};
  const float K2 = 10.30496147f;  // 0.5/0.07 * log2(e)

  // accumulate one j-tile given its 4 B fragments; diagonal handled by
  // wave-uniform post-subtract (taken for <=2 tiles per wave total).
  auto accum = [&](short8 b0, short8 b1, short8 b2, short8 b3, int t, int labj) {
#pragma unroll
    for (int it = 0; it < 2; ++it) {
      floatx4 acc = {0.f, 0.f, 0.f, 0.f};
      acc = __builtin_amdgcn_mfma_f32_16x16x32_bf16(afrag[it][0], b0, acc, 0, 0, 0);
      acc = __builtin_amdgcn_mfma_f32_16x16x32_bf16(afrag[it][1], b1, acc, 0, 0, 0);
      acc = __builtin_amdgcn_mfma_f32_16x16x32_bf16(afrag[it][2], b2, acc, 0, 0, 0);
      acc = __builtin_amdgcn_mfma_f32_16x16x32_bf16(afrag[it][3], b3, acc, 0, 0, 0);
      float ev[4];
#pragma unroll
      for (int r = 0; r < 4; ++r) {
        // C/D layout: row = q*4 + r, col = lane&15 → i = tix*16+q*4+r, j = t*16+col
        float e = __builtin_amdgcn_exp2f(fmaf(acc[r], K2, -K2));  // raw v_exp_f32
        ev[r] = e;
        stot[it][r] += e;
        spos[it][r] += (labj == labi[it][r]) ? e : 0.f;
      }
      if (t == tix[it]) {          // wave-uniform diagonal fix-up
#pragma unroll
        for (int r = 0; r < 4; ++r)
          if (col == q * 4 + r) { stot[it][r] -= ev[r]; spos[it][r] -= ev[r]; }
      }
    }
  };

  const int t0 = blockIdx.y * 32;

  // prologue: stage quad 0 (each thread 4x16B, coalesced)
  {
    const short* g = rns + (size_t)t0 * 2048 + threadIdx.x * 8;
#pragma unroll
    for (int k = 0; k < 4; ++k)
      *(short8*)&lbuf[0][threadIdx.x * 8 + k * 2048] = *(const short8*)(g + k * 2048);
  }
  __syncthreads();

  for (int p = 0; p < 8; ++p) {
    const int cur = p & 1;
    const int t = t0 + p * 4;
    // T14 split: issue next quad's loads into regs NOW, ds_write after compute
    short8 nv0, nv1, nv2, nv3;
    const bool more = (p < 7);
    if (more) {
      const short* g = rns + (size_t)(t + 4) * 2048 + threadIdx.x * 8;
      nv0 = *(const short8*)g;
      nv1 = *(const short8*)(g + 2048);
      nv2 = *(const short8*)(g + 4096);
      nv3 = *(const short8*)(g + 6144);
    }
    int labj[4];
#pragma unroll
    for (int u = 0; u < 4; ++u) labj[u] = labp[(t + u) * 16 + col];

    const short* lb = &lbuf[cur][0];
#pragma unroll
    for (int u = 0; u < 4; ++u) {           // four tiles in the staged quad
      const short* s = lb + u * 2048;
      short8 b0 = *(const short8*)(s + lane * 8);
      short8 b1 = *(const short8*)(s + 512 + lane * 8);
      short8 b2 = *(const short8*)(s + 1024 + lane * 8);
      short8 b3 = *(const short8*)(s + 1536 + lane * 8);
      accum(b0, b1, b2, b3, t + u, labj[u]);
    }

    if (more) {   // vmcnt wait lands HERE, after ~2400cyc of compute
      *(short8*)&lbuf[cur ^ 1][threadIdx.x * 8] = nv0;
      *(short8*)&lbuf[cur ^ 1][threadIdx.x * 8 + 2048] = nv1;
      *(short8*)&lbuf[cur ^ 1][threadIdx.x * 8 + 4096] = nv2;
      *(short8*)&lbuf[cur ^ 1][threadIdx.x * 8 + 6144] = nv3;
    }
    __syncthreads();
  }

  // tail: y=15 also owns padded tile 512 (rows 8192..8207, never diagonal) —
  // read fragments straight from global (coalesced 1KB, one-time)
  if (blockIdx.y == GY - 1) {
    const short* g = rns + (size_t)512 * 2048 + lane * 8;
    short8 b0 = *(const short8*)(g);
    short8 b1 = *(const short8*)(g + 512);
    short8 b2 = *(const short8*)(g + 1024);
    short8 b3 = *(const short8*)(g + 1536);
    accum(b0, b1, b2, b3, 512, labp[512 * 16 + col]);
  }

  // reduce across the 16 column-lanes, then one atomic per i-row per block
  // (waves own disjoint rows -> no cross-wave reduction needed)
#pragma unroll
  for (int it = 0; it < 2; ++it)
#pragma unroll
    for (int r = 0; r < 4; ++r) {
      float tt = stot[it][r], pp = spos[it][r];
#pragma unroll
      for (int m = 1; m <= 8; m <<= 1) {
        tt += __shfl_xor(tt, m);
        pp += __shfl_xor(pp, m);
      }
      if (col == 0) {
        int i = ibase + (w * 2 + it) * 16 + q * 4 + r;
        atomicAdd(&tot[i], tt);
        atomicAdd(&pos[i], pp);
      }
    }
}

// ---- loss kernel: loss = sum(lv * (lv>0.3)) / (sum(lv>0.3) + eps),
//      lv = -log( ((pos/(tot-9*epad))/(hist[lab]+eps)) + eps )
__global__ __launch_bounds__(1024)
void loss_kernel(const float* __restrict__ tot,
                 const float* __restrict__ pos,
                 const int* __restrict__ labels,
                 float* __restrict__ out) {
  __shared__ int hist[NUM_HIST];
  __shared__ float s1[16], s2[16];
  const int tid = threadIdx.x;
  const int lane = tid & 63, wid = tid >> 6;
  if (tid < NUM_HIST) hist[tid] = 0;
  __syncthreads();
  // ballot-based histogram: 7 ballots per 1024-element stripe, no LDS contention
  int c0 = 0, c1 = 0, c2 = 0, c3 = 0, c4 = 0, c5 = 0, c6 = 0;
  for (int i = tid; i < BN; i += 1024) {
    int lab = labels[i];
    unsigned long long m0 = __ballot(lab == 0);
    unsigned long long m1 = __ballot(lab == 1);
    unsigned long long m2 = __ballot(lab == 2);
    unsigned long long m3 = __ballot(lab == 3);
    unsigned long long m4 = __ballot(lab == 4);
    unsigned long long m5 = __ballot(lab == 5);
    unsigned long long m6 = __ballot(lab == 6);
    if (lane == 0) {
      c0 += __popcll(m0); c1 += __popcll(m1); c2 += __popcll(m2);
      c3 += __popcll(m3); c4 += __popcll(m4); c5 += __popcll(m5);
      c6 += __popcll(m6);
    }
  }
  if (lane == 0) {
    atomicAdd(&hist[0], c0); atomicAdd(&hist[1], c1); atomicAdd(&hist[2], c2);
    atomicAdd(&hist[3], c3); atomicAdd(&hist[4], c4); atomicAdd(&hist[5], c5);
    atomicAdd(&hist[6], c6);
  }
  __syncthreads();
  const float K2 = 10.30496147f;
  const float epad9 = 9.0f * exp2f(-K2);   // padded-column excess in tot
  float lsum = 0.f, msum = 0.f;
  for (int i = tid; i < BN; i += 1024) {
    float t = tot[i] - epad9;
    float p = pos[i];
    float c = (float)hist[labels[i]];   // = sum(pos_mask*mask) exactly
    float pr = (p / t) / (c + 1e-8f);
    float lv = -logf(pr + 1e-8f);
    if (lv > 0.3f) { lsum += lv; msum += 1.f; }
  }
#pragma unroll
  for (int m = 1; m < 64; m <<= 1) {
    lsum += __shfl_xor(lsum, m);
    msum += __shfl_xor(msum, m);
  }
  if (lane == 0) { s1[wid] = lsum; s2[wid] = msum; }
  __syncthreads();
  if (wid == 0) {
    float a = (lane < 16) ? s1[lane] : 0.f;
    float b = (lane < 16) ? s2[lane] : 0.f;
#pragma unroll
    for (int m = 1; m < 16; m <<= 1) {
      a += __shfl_xor(a, m);
      b += __shfl_xor(b, m);
    }
    if (lane == 0) out[0] = a / (b + 1e-8f);
  }
}

extern "C" void kernel_launch(void* const* d_in, const int* in_sizes, int n_in,
                              void* d_out, int out_size, void* d_ws, size_t ws_size,
                              hipStream_t stream) {
  const float* reps    = (const float*)d_in[0];  // [8192,128]
  const int*   labels  = (const int*)d_in[1];    // [8192]
  const float* centers = (const float*)d_in[2];  // [7,256]
  const float* fc_w    = (const float*)d_in[3];  // [128,256]
  const float* fc_b    = (const float*)d_in[4];  // [128]
  float* out = (float*)d_out;

  char* ws = (char*)d_ws;
  int* labp   = (int*)(ws + 4096);                       // 8208*4
  __hip_bfloat16* rnt = (__hip_bfloat16*)(ws + 40960);   // 513 tiles * 4KB = 2101248 B
  float* tot = (float*)(ws + 40960 + 2101248);           // 8192*4
  float* pos = tot + BN;                                 // 8192*4 (contiguous after tot)

  prep_kernel<<<2049, 256, 0, stream>>>(reps, labels, centers, fc_w, fc_b, rnt, labp, tot);
  main_kernel<<<dim3(GX2, GY), 256, 0, stream>>>(rnt, labp, tot, pos);
  loss_kernel<<<1, 1024, 0, stream>>>(tot, pos, labels, out);
}